// Round 1
// baseline (644.132 us; speedup 1.0000x reference)
//
#include <hip/hip_runtime.h>
#include <cmath>

#define HW   16384
#define Wd   128
#define Hd   128
#define NB   4

// -------- weight repack: src [O][C][3][3] -> dst [9][C][OT] at channel base obase --------
__global__ void repack_kernel(const float* __restrict__ src, float* __restrict__ dst,
                              int O, int C, int OT, int obase) {
    int idx = blockIdx.x * 256 + threadIdx.x;
    int total = O * C * 9;
    if (idx >= total) return;
    int j = idx / (O * C);
    int rem = idx - j * O * C;
    int c = rem / O;
    int o = rem - c * O;
    dst[(j * C + c) * OT + obase + o] = src[(o * C + c) * 9 + j];
}

__global__ void bias_concat_kernel(const float* __restrict__ b1, const float* __restrict__ b2,
                                   float* __restrict__ dst) {
    int t = threadIdx.x;
    if (t < 27) dst[t] = b1[t];
    else if (t < 54) dst[t] = b2[t - 27];
}

// -------- generic direct 3x3 conv, SAME padding. thread = 1 pixel x OCHUNK channels --------
// wt layout [9][CIN][OTOT]; out layout [B][outChanTot][HW] written at channel ochanBase+oc0
template<int CIN, int OCHUNK>
__global__ __launch_bounds__(256) void conv3x3_kernel(
    const float* __restrict__ x, const float* __restrict__ wt,
    const float* __restrict__ bias, float* __restrict__ out,
    int OTOT, int ochanBase, int outChanTot)
{
    int pix = blockIdx.x * 256 + threadIdx.x;
    int oc0 = blockIdx.y * OCHUNK;
    int b = pix >> 14;
    int p = pix & (HW - 1);
    int h = p >> 7;
    int w = p & (Wd - 1);

    float acc[OCHUNK];
#pragma unroll
    for (int i = 0; i < OCHUNK; i++) acc[i] = 0.f;

    const float* xb = x + (size_t)b * CIN * HW;

#pragma unroll
    for (int j = 0; j < 9; j++) {
        int dy = j / 3 - 1, dx = j % 3 - 1;
        int hh = h + dy, ww = w + dx;
        if (hh >= 0 && hh < Hd && ww >= 0 && ww < Wd) {
            const float* xp = xb + hh * Wd + ww;
            const float* wj = wt + (size_t)j * CIN * OTOT + oc0;
#pragma unroll 4
            for (int c = 0; c < CIN; c++) {
                float v = xp[c * HW];
#pragma unroll
                for (int i = 0; i < OCHUNK; i++)
                    acc[i] = fmaf(wj[c * OTOT + i], v, acc[i]);
            }
        }
    }

    size_t ob = ((size_t)b * outChanTot + ochanBase + oc0) * HW + p;
#pragma unroll
    for (int i = 0; i < OCHUNK; i++)
        out[ob + (size_t)i * HW] = acc[i] + bias[oc0 + i];
}

// -------- DCNv2: thread = 1 pixel x 32 out channels (grid.y = 2) --------
// om layout [B][54][HW] (raw conv output + bias); channels omOff..omOff+26 used:
//   off_y[k] = ch 2k, off_x[k] = ch 2k+1, mask[k] = sigmoid(ch 18+k)
// wt layout [9][64][64] = [k][cin][cout]
template<bool LEAKY, bool RESID>
__global__ __launch_bounds__(256) void dcn_kernel(
    const float* __restrict__ xsrc, const float* __restrict__ om, int omOff,
    const float* __restrict__ wt, const float* __restrict__ bias,
    const float* __restrict__ resid, float* __restrict__ out)
{
    int pix = blockIdx.x * 256 + threadIdx.x;
    int oc0 = blockIdx.y * 32;
    int b = pix >> 14;
    int p = pix & (HW - 1);
    int h = p >> 7;
    int w = p & (Wd - 1);

    const float* omb = om + ((size_t)b * 54 + omOff) * HW + p;
    const float* xb  = xsrc + (size_t)b * 64 * HW;

    float acc[32];
#pragma unroll
    for (int i = 0; i < 32; i++) acc[i] = 0.f;

    for (int k = 0; k < 9; k++) {
        float oy = omb[(2 * k) * HW];
        float ox = omb[(2 * k + 1) * HW];
        float mv = omb[(18 + k) * HW];
        float mk = 1.f / (1.f + __expf(-mv));

        float ys = (float)(h + k / 3 - 1) + oy;
        float xs = (float)(w + k % 3 - 1) + ox;
        float y0f = floorf(ys), x0f = floorf(xs);
        float fy = ys - y0f, fx = xs - x0f;
        int y0 = (int)y0f, x0 = (int)x0f;
        int y1 = y0 + 1, x1 = x0 + 1;

        bool vy0 = (y0 >= 0) && (y0 < Hd);
        bool vy1 = (y1 >= 0) && (y1 < Hd);
        bool vx0 = (x0 >= 0) && (x0 < Wd);
        bool vx1 = (x1 >= 0) && (x1 < Wd);

        float w00 = (vy0 && vx0) ? (1.f - fy) * (1.f - fx) * mk : 0.f;
        float w01 = (vy0 && vx1) ? (1.f - fy) * fx * mk : 0.f;
        float w10 = (vy1 && vx0) ? fy * (1.f - fx) * mk : 0.f;
        float w11 = (vy1 && vx1) ? fy * fx * mk : 0.f;

        int iy0 = min(max(y0, 0), Hd - 1) * Wd;
        int iy1 = min(max(y1, 0), Hd - 1) * Wd;
        int ix0 = min(max(x0, 0), Wd - 1);
        int ix1 = min(max(x1, 0), Wd - 1);
        int o00 = iy0 + ix0, o01 = iy0 + ix1, o10 = iy1 + ix0, o11 = iy1 + ix1;

        const float* wk = wt + (size_t)k * 64 * 64 + oc0;
#pragma unroll 4
        for (int c = 0; c < 64; c++) {
            const float* xc = xb + c * HW;
            float t = w00 * xc[o00] + w01 * xc[o01] + w10 * xc[o10] + w11 * xc[o11];
#pragma unroll
            for (int i = 0; i < 32; i++)
                acc[i] = fmaf(wk[c * 64 + i], t, acc[i]);
        }
    }

    size_t obase = ((size_t)b * 64 + oc0) * HW + p;
#pragma unroll
    for (int i = 0; i < 32; i++) {
        float v = acc[i] + bias[oc0 + i];
        if (LEAKY) v = (v >= 0.f) ? v : 0.01f * v;
        if (RESID) v += resid[obase + (size_t)i * HW];
        out[obase + (size_t)i * HW] = v;
    }
}

extern "C" void kernel_launch(void* const* d_in, const int* in_sizes, int n_in,
                              void* d_out, int out_size, void* d_ws, size_t ws_size,
                              hipStream_t stream)
{
    const float* input  = (const float*)d_in[0];
    const float* offset = (const float*)d_in[1];
    const float* w_off1 = (const float*)d_in[2];
    const float* b_off1 = (const float*)d_in[3];
    const float* w1     = (const float*)d_in[4];
    const float* b1     = (const float*)d_in[5];
    const float* w_off2 = (const float*)d_in[6];
    const float* b_off2 = (const float*)d_in[7];
    const float* w2     = (const float*)d_in[8];
    const float* b2     = (const float*)d_in[9];
    const float* w_last = (const float*)d_in[10];
    const float* b_last = (const float*)d_in[11];
    float* out = (float*)d_out;

    float* ws     = (float*)d_ws;
    float* om     = ws;                     // 4*54*16384 = 3538944
    float* x1     = om + 3538944;           // 4194304
    float* x2     = x1 + 4194304;           // 4194304
    float* wtoffC = x2 + 4194304;           // 9*32*54 = 15552
    float* bofC   = wtoffC + 15552;         // 64
    float* wt1    = bofC + 64;              // 36864
    float* wt2    = wt1 + 36864;            // 36864
    float* wtl    = wt2 + 36864;            // 36864

    // weight repacks (tiny)
    repack_kernel<<<dim3((27*32*9 + 255) / 256), 256, 0, stream>>>(w_off1, wtoffC, 27, 32, 54, 0);
    repack_kernel<<<dim3((27*32*9 + 255) / 256), 256, 0, stream>>>(w_off2, wtoffC, 27, 32, 54, 27);
    repack_kernel<<<dim3((64*64*9 + 255) / 256), 256, 0, stream>>>(w1, wt1, 64, 64, 64, 0);
    repack_kernel<<<dim3((64*64*9 + 255) / 256), 256, 0, stream>>>(w2, wt2, 64, 64, 64, 0);
    repack_kernel<<<dim3((64*64*9 + 255) / 256), 256, 0, stream>>>(w_last, wtl, 64, 64, 64, 0);
    bias_concat_kernel<<<dim3(1), 64, 0, stream>>>(b_off1, b_off2, bofC);

    const int PIXBLOCKS = NB * HW / 256;   // 256

    // both offset convs in one launch: blockIdx.y in {0,1} -> channels 0..26 / 27..53
    conv3x3_kernel<32, 27><<<dim3(PIXBLOCKS, 2), 256, 0, stream>>>(
        offset, wtoffC, bofC, om, 54, 0, 54);

    // DCN 1: sample from input, leaky-relu epilogue -> x1
    dcn_kernel<true, false><<<dim3(PIXBLOCKS, 2), 256, 0, stream>>>(
        input, om, 0, wt1, b1, nullptr, x1);

    // DCN 2: sample from x1, + input residual -> x2
    dcn_kernel<false, true><<<dim3(PIXBLOCKS, 2), 256, 0, stream>>>(
        x1, om, 27, wt2, b2, input, x2);

    // final conv
    conv3x3_kernel<64, 32><<<dim3(PIXBLOCKS, 2), 256, 0, stream>>>(
        x2, wtl, b_last, out, 64, 0, 64);
}

// Round 2
// 257.930 us; speedup vs baseline: 2.4973x; 2.4973x over previous
//
#include <hip/hip_runtime.h>
#include <cmath>

#define HW   16384
#define Wd   128
#define Hd   128
#define NB   4

typedef __attribute__((ext_vector_type(8))) short bf16x8;
typedef __attribute__((ext_vector_type(4))) float f32x4;

__device__ inline unsigned short f2bf(float f) {
    unsigned u = __builtin_bit_cast(unsigned, f);
    unsigned r = (u + 0x7FFFu + ((u >> 16) & 1u)) >> 16;
    return (unsigned short)r;
}

// ---------- weight repack into MFMA A-fragment-linear bf16 ----------
// dst layout: [9][4 mtile][KS][64 lane][8 e] bf16
// element (k,m,ks,lane,e) <- w[oc][c][k] with oc=m*16+(lane&15), c=ks*32+(lane>>4)*8+e
// oc < Osplit from src1, else src2 (oc-Osplit); zero-pad oc >= O or c >= CIN.
__global__ void repack_mfma(const float* __restrict__ src1, const float* __restrict__ src2,
                            int Osplit, int O, int CIN, int KS, unsigned short* __restrict__ dst) {
    int idx = blockIdx.x * 256 + threadIdx.x;
    int total = 9 * 4 * KS * 64 * 8;
    if (idx >= total) return;
    int e    = idx & 7;
    int lane = (idx >> 3) & 63;
    int ks   = (idx >> 9) % KS;
    int m    = (idx / (512 * KS)) & 3;
    int k    = idx / (2048 * KS);
    int oc = m * 16 + (lane & 15);
    int c  = ks * 32 + (lane >> 4) * 8 + e;
    float v = 0.f;
    if (oc < O && c < CIN) {
        const float* s = (oc < Osplit) ? src1 + ((size_t)oc * CIN + c) * 9 + k
                                       : src2 + ((size_t)(oc - Osplit) * CIN + c) * 9 + k;
        v = *s;
    }
    dst[idx] = f2bf(v);
}

__global__ void bias_concat_kernel(const float* __restrict__ b1, const float* __restrict__ b2,
                                   float* __restrict__ dst) {
    int t = threadIdx.x;
    if (t < 27) dst[t] = b1[t];
    else if (t < 54) dst[t] = b2[t - 27];
}

// ---------- MFMA conv3x3 (implicit GEMM) ----------
// block: 128 px (one image row) x 64 oc; 512 threads (8 waves).
// LDS S[px][c] bf16, 16B granules XOR-swizzled by (px&7).
template<int CIN, int OCT>
__global__ __launch_bounds__(512) void conv_mfma_kernel(
    const float* __restrict__ x, const unsigned short* __restrict__ wf,
    const float* __restrict__ bias, float* __restrict__ out)
{
    constexpr int KS = CIN / 32;
    constexpr int GRAN = CIN / 8;            // 16B granules per LDS row
    __shared__ __align__(16) unsigned short smem[128 * CIN];

    int t = threadIdx.x;
    int lane = t & 63;
    int wv = t >> 6;
    int px0 = blockIdx.x * 128;
    int b = px0 >> 14;
    int row = (px0 >> 7) & 127;              // uniform per block
    const float* xb = x + (size_t)b * CIN * HW;

    int spx = t & 127;                       // sampler pixel (column, since block = 1 row)
    int cq = t >> 7;                         // channel quarter

    f32x4 acc[4];
#pragma unroll
    for (int m = 0; m < 4; m++) acc[m] = (f32x4){0.f, 0.f, 0.f, 0.f};

    for (int k = 0; k < 9; k++) {
        // ---- stage: S[c][px] = x[c][p + (dy,dx)] (0 if OOB) ----
        {
            int dy = k / 3 - 1, dx = k % 3 - 1;
            int hh = row + dy, ww = spx + dx;
            bool ok = (hh >= 0) & (hh < Hd) & (ww >= 0) & (ww < Wd);
            int pp = hh * Wd + ww;
#pragma unroll
            for (int cg = 0; cg < CIN / 32; cg++) {
                int c0 = cq * (CIN / 4) + cg * 8;
                bf16x8 hv;
#pragma unroll
                for (int e = 0; e < 8; e++) {
                    int c = c0 + e;
                    float v = ok ? xb[(size_t)c * HW + pp] : 0.f;
                    hv[e] = (short)f2bf(v);
                }
                int gran = ((c0 >> 3) ^ (spx & 7)) & (GRAN - 1);
                *(bf16x8*)(&smem[spx * CIN + gran * 8]) = hv;
            }
        }
        __syncthreads();
        // ---- GEMM ----
        {
            const bf16x8* wfv = (const bf16x8*)wf;
            bf16x8 aF[4][KS];
#pragma unroll
            for (int m = 0; m < 4; m++)
#pragma unroll
                for (int ks = 0; ks < KS; ks++)
                    aF[m][ks] = wfv[((k * 4 + m) * KS + ks) * 64 + lane];
            int bpx = wv * 16 + (lane & 15);
            int g = lane >> 4;
#pragma unroll
            for (int ks = 0; ks < KS; ks++) {
                int gran = ((ks * 4 + g) ^ (bpx & 7)) & (GRAN - 1);
                bf16x8 bF = *(const bf16x8*)(&smem[bpx * CIN + gran * 8]);
#pragma unroll
                for (int m = 0; m < 4; m++)
                    acc[m] = __builtin_amdgcn_mfma_f32_16x16x32_bf16(aF[m][ks], bF, acc[m], 0, 0, 0);
            }
        }
        __syncthreads();
    }

    // ---- epilogue: D row=(lane>>4)*4+r (oc), col=lane&15 (px) ----
    int opx = px0 + wv * 16 + (lane & 15);
    int ob = opx >> 14;
    int op = opx & 16383;
#pragma unroll
    for (int m = 0; m < 4; m++) {
        int ocb = m * 16 + (lane >> 4) * 4;
#pragma unroll
        for (int r = 0; r < 4; r++) {
            int oc = ocb + r;
            if (OCT == 64 || oc < OCT)
                out[((size_t)ob * OCT + oc) * HW + op] = acc[m][r] + bias[oc];
        }
    }
}

// ---------- MFMA DCNv2 ----------
// EPI: 0 = leaky-relu, 1 = +residual
template<int EPI>
__global__ __launch_bounds__(512) void dcn_mfma_kernel(
    const float* __restrict__ xsrc, const float* __restrict__ om, int omOff,
    const unsigned short* __restrict__ wf, const float* __restrict__ bias,
    const float* __restrict__ resid, float* __restrict__ out)
{
    __shared__ __align__(16) unsigned short smem[128 * 64];

    int t = threadIdx.x;
    int lane = t & 63;
    int wv = t >> 6;
    int px0 = blockIdx.x * 128;
    int b = px0 >> 14;
    int row = (px0 >> 7) & 127;
    int spx = t & 127;
    int cq = t >> 7;
    int p = (px0 & 16383) + spx;

    const float* xb = xsrc + (size_t)b * 64 * HW;
    const float* omb = om + ((size_t)b * 54 + omOff) * HW + p;

    f32x4 acc[4];
#pragma unroll
    for (int m = 0; m < 4; m++) acc[m] = (f32x4){0.f, 0.f, 0.f, 0.f};

    for (int k = 0; k < 9; k++) {
        // ---- sampling params (per pixel, shared across this thread's 16 c) ----
        {
            float oy = omb[(size_t)(2 * k) * HW];
            float ox = omb[(size_t)(2 * k + 1) * HW];
            float mv = omb[(size_t)(18 + k) * HW];
            float mk = 1.f / (1.f + __expf(-mv));

            float ys = (float)(row + k / 3 - 1) + oy;
            float xs = (float)(spx + k % 3 - 1) + ox;
            float y0f = floorf(ys), x0f = floorf(xs);
            float fy = ys - y0f, fx = xs - x0f;
            int y0 = (int)y0f, x0 = (int)x0f;
            int y1 = y0 + 1, x1 = x0 + 1;

            bool vy0 = (y0 >= 0) & (y0 < Hd);
            bool vy1 = (y1 >= 0) & (y1 < Hd);
            bool vx0 = (x0 >= 0) & (x0 < Wd);
            bool vx1 = (x1 >= 0) & (x1 < Wd);

            float w00 = (vy0 && vx0) ? (1.f - fy) * (1.f - fx) * mk : 0.f;
            float w01 = (vy0 && vx1) ? (1.f - fy) * fx * mk : 0.f;
            float w10 = (vy1 && vx0) ? fy * (1.f - fx) * mk : 0.f;
            float w11 = (vy1 && vx1) ? fy * fx * mk : 0.f;

            int iy0 = min(max(y0, 0), Hd - 1) * Wd;
            int iy1 = min(max(y1, 0), Hd - 1) * Wd;
            int ix0 = min(max(x0, 0), Wd - 1);
            int ix1 = min(max(x1, 0), Wd - 1);
            int o00 = iy0 + ix0, o01 = iy0 + ix1, o10 = iy1 + ix0, o11 = iy1 + ix1;

#pragma unroll
            for (int cg = 0; cg < 2; cg++) {
                int c0 = cq * 16 + cg * 8;
                bf16x8 hv;
#pragma unroll
                for (int e = 0; e < 8; e++) {
                    const float* xc = xb + (size_t)(c0 + e) * HW;
                    float v = w00 * xc[o00] + w01 * xc[o01] + w10 * xc[o10] + w11 * xc[o11];
                    hv[e] = (short)f2bf(v);
                }
                int gran = ((c0 >> 3) ^ (spx & 7)) & 7;
                *(bf16x8*)(&smem[spx * 64 + gran * 8]) = hv;
            }
        }
        __syncthreads();
        // ---- GEMM (K=64 per tap) ----
        {
            const bf16x8* wfv = (const bf16x8*)wf;
            bf16x8 aF[4][2];
#pragma unroll
            for (int m = 0; m < 4; m++)
#pragma unroll
                for (int ks = 0; ks < 2; ks++)
                    aF[m][ks] = wfv[((k * 4 + m) * 2 + ks) * 64 + lane];
            int bpx = wv * 16 + (lane & 15);
            int g = lane >> 4;
#pragma unroll
            for (int ks = 0; ks < 2; ks++) {
                int gran = ((ks * 4 + g) ^ (bpx & 7)) & 7;
                bf16x8 bF = *(const bf16x8*)(&smem[bpx * 64 + gran * 8]);
#pragma unroll
                for (int m = 0; m < 4; m++)
                    acc[m] = __builtin_amdgcn_mfma_f32_16x16x32_bf16(aF[m][ks], bF, acc[m], 0, 0, 0);
            }
        }
        __syncthreads();
    }

    int opx = px0 + wv * 16 + (lane & 15);
    int ob = opx >> 14;
    int op = opx & 16383;
#pragma unroll
    for (int m = 0; m < 4; m++) {
        int ocb = m * 16 + (lane >> 4) * 4;
#pragma unroll
        for (int r = 0; r < 4; r++) {
            int oc = ocb + r;
            float v = acc[m][r] + bias[oc];
            if (EPI == 0) v = (v >= 0.f) ? v : 0.01f * v;
            size_t oaddr = ((size_t)ob * 64 + oc) * HW + op;
            if (EPI == 1) v += resid[oaddr];
            out[oaddr] = v;
        }
    }
}

extern "C" void kernel_launch(void* const* d_in, const int* in_sizes, int n_in,
                              void* d_out, int out_size, void* d_ws, size_t ws_size,
                              hipStream_t stream)
{
    const float* input  = (const float*)d_in[0];
    const float* offset = (const float*)d_in[1];
    const float* w_off1 = (const float*)d_in[2];
    const float* b_off1 = (const float*)d_in[3];
    const float* w1     = (const float*)d_in[4];
    const float* b1     = (const float*)d_in[5];
    const float* w_off2 = (const float*)d_in[6];
    const float* b_off2 = (const float*)d_in[7];
    const float* w2     = (const float*)d_in[8];
    const float* b2     = (const float*)d_in[9];
    const float* w_last = (const float*)d_in[10];
    const float* b_last = (const float*)d_in[11];
    float* out = (float*)d_out;

    float* ws = (float*)d_ws;
    float* om = ws;                              // 4*54*16384 = 3538944 f
    float* x1 = om + 3538944;                    // 4194304 f
    float* x2 = x1 + 4194304;                    // 4194304 f
    unsigned short* wfo = (unsigned short*)(x2 + 4194304);   // 18432 ush
    unsigned short* wf1 = wfo + 18432;           // 36864 ush
    unsigned short* wf2 = wf1 + 36864;           // 36864 ush
    unsigned short* wfl = wf2 + 36864;           // 36864 ush
    float* bias54 = (float*)(wfl + 36864);       // 64 f

    // weight repacks (tiny)
    repack_mfma<<<dim3(72),  256, 0, stream>>>(w_off1, w_off2, 27, 54, 32, 1, wfo);
    repack_mfma<<<dim3(144), 256, 0, stream>>>(w1, w1, 64, 64, 64, 2, wf1);
    repack_mfma<<<dim3(144), 256, 0, stream>>>(w2, w2, 64, 64, 64, 2, wf2);
    repack_mfma<<<dim3(144), 256, 0, stream>>>(w_last, w_last, 64, 64, 64, 2, wfl);
    bias_concat_kernel<<<dim3(1), 64, 0, stream>>>(b_off1, b_off2, bias54);

    const int BLOCKS = NB * HW / 128;            // 512

    // offset conv (both weight sets fused, 54 output channels)
    conv_mfma_kernel<32, 54><<<dim3(BLOCKS), 512, 0, stream>>>(offset, wfo, bias54, om);
    // DCN 1: sample input, leaky -> x1
    dcn_mfma_kernel<0><<<dim3(BLOCKS), 512, 0, stream>>>(input, om, 0, wf1, b1, nullptr, x1);
    // DCN 2: sample x1, + input residual -> x2
    dcn_mfma_kernel<1><<<dim3(BLOCKS), 512, 0, stream>>>(x1, om, 27, wf2, b2, input, x2);
    // final conv
    conv_mfma_kernel<64, 64><<<dim3(BLOCKS), 512, 0, stream>>>(x2, wfl, b_last, out);
}

// Round 3
// 153.175 us; speedup vs baseline: 4.2052x; 1.6839x over previous
//
#include <hip/hip_runtime.h>
#include <cmath>

#define HW   16384
#define Wd   128
#define Hd   128
#define NB   4

typedef __attribute__((ext_vector_type(8))) short bf16x8;
typedef __attribute__((ext_vector_type(4))) float f32x4;
typedef __attribute__((ext_vector_type(4))) unsigned int u32x4;

__device__ inline unsigned short f2bf(float f) {
    unsigned u = __builtin_bit_cast(unsigned, f);
    unsigned r = (u + 0x7FFFu + ((u >> 16) & 1u)) >> 16;
    return (unsigned short)r;
}
__device__ inline float bflo(unsigned w) { return __builtin_bit_cast(float, w << 16); }
__device__ inline float bfhi(unsigned w) { return __builtin_bit_cast(float, w & 0xFFFF0000u); }

// ---------- weight repack into MFMA A-fragment-linear bf16 (unchanged layout) ----------
// dst: [9][4 m][KS][64 lane][8 e]; (k,m,ks,lane,e) <- w[oc][c][k], oc=m*16+(lane&15),
// c=ks*32+(lane>>4)*8+e; src1 for oc<Osplit else src2; zero-pad OOB.
__global__ void repack_mfma(const float* __restrict__ src1, const float* __restrict__ src2,
                            int Osplit, int O, int CIN, int KS, unsigned short* __restrict__ dst) {
    int idx = blockIdx.x * 256 + threadIdx.x;
    int total = 9 * 4 * KS * 64 * 8;
    if (idx >= total) return;
    int e    = idx & 7;
    int lane = (idx >> 3) & 63;
    int ks   = (idx >> 9) % KS;
    int m    = (idx / (512 * KS)) & 3;
    int k    = idx / (2048 * KS);
    int oc = m * 16 + (lane & 15);
    int c  = ks * 32 + (lane >> 4) * 8 + e;
    float v = 0.f;
    if (oc < O && c < CIN) {
        const float* s = (oc < Osplit) ? src1 + ((size_t)oc * CIN + c) * 9 + k
                                       : src2 + ((size_t)(oc - Osplit) * CIN + c) * 9 + k;
        v = *s;
    }
    dst[idx] = f2bf(v);
}

__global__ void bias_concat_kernel(const float* __restrict__ b1, const float* __restrict__ b2,
                                   float* __restrict__ dst) {
    int t = threadIdx.x;
    if (t < 27) dst[t] = b1[t];
    else if (t < 54) dst[t] = b2[t - 27];
}

// ---------- NCHW fp32 -> NHWC bf16 for input (64ch) and offset (32ch) ----------
__global__ __launch_bounds__(256) void to_nhwc(const float* __restrict__ xin,
                                               const float* __restrict__ off,
                                               unsigned short* __restrict__ xn,
                                               unsigned short* __restrict__ offn) {
    int t = blockIdx.x * 256 + threadIdx.x;
    if (t < 65536) {
        int b = t >> 14, p = t & 16383;
        const float* s = xin + ((size_t)b * 64) * HW + p;
        unsigned short* d = xn + (size_t)t * 64;
#pragma unroll 8
        for (int c = 0; c < 64; c++) d[c] = f2bf(s[(size_t)c * HW]);
    } else {
        int u = t - 65536;
        int b = u >> 14, p = u & 16383;
        const float* s = off + ((size_t)b * 32) * HW + p;
        unsigned short* d = offn + (size_t)u * 32;
#pragma unroll 8
        for (int c = 0; c < 32; c++) d[c] = f2bf(s[(size_t)c * HW]);
    }
}

// ---------- LDS-free direct conv3x3: B-fragments straight from NHWC global ----------
// block = 256 thr = 4 waves; wave owns 16 px (quarter-row); out NCHW fp32.
template<int CIN, int OCT>
__global__ __launch_bounds__(256) void conv_direct(
    const unsigned short* __restrict__ xn, const unsigned short* __restrict__ wf,
    const float* __restrict__ bias, float* __restrict__ out)
{
    constexpr int KS = CIN / 32;
    int lb = ((blockIdx.x & 7) << 7) | (blockIdx.x >> 3);   // XCD-chunked swizzle (1024%8==0)
    int t = threadIdx.x;
    int lane = t & 63, wv = t >> 6;
    int px = lb * 64 + wv * 16 + (lane & 15);
    int b = px >> 14, p = px & 16383;
    int row = p >> 7, col = p & 127;
    int cg = lane >> 4;

    const bf16x8* wfv = (const bf16x8*)wf;
    f32x4 acc[4];
#pragma unroll
    for (int m = 0; m < 4; m++) acc[m] = (f32x4){0.f, 0.f, 0.f, 0.f};

#pragma unroll
    for (int k = 0; k < 9; k++) {
        int dy = k / 3 - 1, dx = k % 3 - 1;
        int hh = row + dy, ww = col + dx;
        bool ok = (hh >= 0) & (hh < Hd) & (ww >= 0) & (ww < Wd);
        size_t base = ((size_t)(b << 14) + hh * Wd + ww) * CIN;

        bf16x8 aF[4 * KS];
#pragma unroll
        for (int m = 0; m < 4; m++)
#pragma unroll
            for (int ks = 0; ks < KS; ks++)
                aF[m * KS + ks] = wfv[((k * 4 + m) * KS + ks) * 64 + lane];

#pragma unroll
        for (int ks = 0; ks < KS; ks++) {
            bf16x8 bF = (bf16x8){0, 0, 0, 0, 0, 0, 0, 0};
            if (ok) bF = *(const bf16x8*)(xn + base + ks * 32 + cg * 8);
#pragma unroll
            for (int m = 0; m < 4; m++)
                acc[m] = __builtin_amdgcn_mfma_f32_16x16x32_bf16(aF[m * KS + ks], bF, acc[m], 0, 0, 0);
        }
    }

    // C/D: col = lane&15 (px), row oc = (lane>>4)*4 + r + m*16
#pragma unroll
    for (int m = 0; m < 4; m++) {
        int ocb = m * 16 + cg * 4;
#pragma unroll
        for (int r = 0; r < 4; r++) {
            int oc = ocb + r;
            if (OCT == 64 || oc < OCT)
                out[((size_t)b * OCT + oc) * HW + p] = acc[m][r] + bias[oc];
        }
    }
}

// ---------- LDS-free direct DCNv2: per-lane bilinear B-fragments from NHWC ----------
// EPI 0: leaky -> outn (NHWC bf16). EPI 1: +resid(NCHW fp32) -> outn (NHWC bf16).
template<int EPI>
__global__ __launch_bounds__(256) void dcn_direct(
    const unsigned short* __restrict__ xn, const float* __restrict__ om, int omOff,
    const unsigned short* __restrict__ wf, const float* __restrict__ bias,
    const float* __restrict__ resid, unsigned short* __restrict__ outn)
{
    int lb = ((blockIdx.x & 7) << 7) | (blockIdx.x >> 3);
    int t = threadIdx.x;
    int lane = t & 63, wv = t >> 6;
    int px = lb * 64 + wv * 16 + (lane & 15);
    int b = px >> 14, p = px & 16383;
    int row = p >> 7, col = p & 127;
    int cg = lane >> 4;

    const float* omb = om + ((size_t)b * 54 + omOff) * HW + p;
    const unsigned short* xb = xn + ((size_t)(b << 14)) * 64;
    const bf16x8* wfv = (const bf16x8*)wf;

    f32x4 acc[4];
#pragma unroll
    for (int m = 0; m < 4; m++) acc[m] = (f32x4){0.f, 0.f, 0.f, 0.f};

#pragma unroll
    for (int k = 0; k < 9; k++) {
        float oy = omb[(size_t)(2 * k) * HW];
        float ox = omb[(size_t)(2 * k + 1) * HW];
        float mv = omb[(size_t)(18 + k) * HW];
        float mk = 1.f / (1.f + __expf(-mv));

        float ys = (float)(row + k / 3 - 1) + oy;
        float xs = (float)(col + k % 3 - 1) + ox;
        float y0f = floorf(ys), x0f = floorf(xs);
        float fy = ys - y0f, fx = xs - x0f;
        int y0 = (int)y0f, x0 = (int)x0f;
        int y1 = y0 + 1, x1 = x0 + 1;

        bool vy0 = (y0 >= 0) & (y0 < Hd);
        bool vy1 = (y1 >= 0) & (y1 < Hd);
        bool vx0 = (x0 >= 0) & (x0 < Wd);
        bool vx1 = (x1 >= 0) & (x1 < Wd);

        float w00 = (vy0 && vx0) ? (1.f - fy) * (1.f - fx) * mk : 0.f;
        float w01 = (vy0 && vx1) ? (1.f - fy) * fx * mk : 0.f;
        float w10 = (vy1 && vx0) ? fy * (1.f - fx) * mk : 0.f;
        float w11 = (vy1 && vx1) ? fy * fx * mk : 0.f;

        int iy0 = min(max(y0, 0), Hd - 1) * Wd;
        int iy1 = min(max(y1, 0), Hd - 1) * Wd;
        int ix0 = min(max(x0, 0), Wd - 1);
        int ix1 = min(max(x1, 0), Wd - 1);
        const unsigned short* p00 = xb + (size_t)(iy0 + ix0) * 64;
        const unsigned short* p01 = xb + (size_t)(iy0 + ix1) * 64;
        const unsigned short* p10 = xb + (size_t)(iy1 + ix0) * 64;
        const unsigned short* p11 = xb + (size_t)(iy1 + ix1) * 64;

        bf16x8 aF[8];
#pragma unroll
        for (int m = 0; m < 4; m++)
#pragma unroll
            for (int ks = 0; ks < 2; ks++)
                aF[m * 2 + ks] = wfv[((k * 4 + m) * 2 + ks) * 64 + lane];

#pragma unroll
        for (int ks = 0; ks < 2; ks++) {
            int c0 = ks * 32 + cg * 8;
            u32x4 a00 = *(const u32x4*)(p00 + c0);
            u32x4 a01 = *(const u32x4*)(p01 + c0);
            u32x4 a10 = *(const u32x4*)(p10 + c0);
            u32x4 a11 = *(const u32x4*)(p11 + c0);
            unsigned ow[4];
#pragma unroll
            for (int wd = 0; wd < 4; wd++) {
                float slo = w00 * bflo(a00[wd]);
                slo = fmaf(w01, bflo(a01[wd]), slo);
                slo = fmaf(w10, bflo(a10[wd]), slo);
                slo = fmaf(w11, bflo(a11[wd]), slo);
                float shi = w00 * bfhi(a00[wd]);
                shi = fmaf(w01, bfhi(a01[wd]), shi);
                shi = fmaf(w10, bfhi(a10[wd]), shi);
                shi = fmaf(w11, bfhi(a11[wd]), shi);
                ow[wd] = (unsigned)f2bf(slo) | ((unsigned)f2bf(shi) << 16);
            }
            bf16x8 bF = __builtin_bit_cast(bf16x8, *(u32x4*)ow);
#pragma unroll
            for (int m = 0; m < 4; m++)
                acc[m] = __builtin_amdgcn_mfma_f32_16x16x32_bf16(aF[m * 2 + ks], bF, acc[m], 0, 0, 0);
        }
    }

    // epilogue: write NHWC bf16 (px = our lane px); 4x ushort4 (8B) stores
    unsigned short* drow = outn + (size_t)px * 64;
#pragma unroll
    for (int m = 0; m < 4; m++) {
        int ocb = m * 16 + cg * 4;
        unsigned short pk[4];
#pragma unroll
        for (int r = 0; r < 4; r++) {
            int oc = ocb + r;
            float v = acc[m][r] + bias[oc];
            if (EPI == 0) v = (v >= 0.f) ? v : 0.01f * v;
            if (EPI == 1) v += resid[((size_t)b * 64 + oc) * HW + p];
            pk[r] = f2bf(v);
        }
        *(ushort4*)(drow + ocb) = *(ushort4*)pk;
    }
}

extern "C" void kernel_launch(void* const* d_in, const int* in_sizes, int n_in,
                              void* d_out, int out_size, void* d_ws, size_t ws_size,
                              hipStream_t stream)
{
    const float* input  = (const float*)d_in[0];
    const float* offset = (const float*)d_in[1];
    const float* w_off1 = (const float*)d_in[2];
    const float* b_off1 = (const float*)d_in[3];
    const float* w1     = (const float*)d_in[4];
    const float* b1     = (const float*)d_in[5];
    const float* w_off2 = (const float*)d_in[6];
    const float* b_off2 = (const float*)d_in[7];
    const float* w2     = (const float*)d_in[8];
    const float* b2     = (const float*)d_in[9];
    const float* w_last = (const float*)d_in[10];
    const float* b_last = (const float*)d_in[11];
    float* out = (float*)d_out;

    float* ws = (float*)d_ws;
    float* om = ws;                                        // 3,538,944 f
    unsigned short* xn   = (unsigned short*)(om + 3538944);   // 4,194,304 ush
    unsigned short* offn = xn + 4194304;                   // 2,097,152 ush
    unsigned short* x1n  = offn + 2097152;                 // 4,194,304 ush
    unsigned short* x2n  = x1n + 4194304;                  // 4,194,304 ush
    unsigned short* wfo  = x2n + 4194304;                  // 18,432 ush
    unsigned short* wf1  = wfo + 18432;                    // 36,864 ush
    unsigned short* wf2  = wf1 + 36864;                    // 36,864 ush
    unsigned short* wfl  = wf2 + 36864;                    // 36,864 ush
    float* bias54 = (float*)(wfl + 36864);                 // 64 f

    repack_mfma<<<dim3(72),  256, 0, stream>>>(w_off1, w_off2, 27, 54, 32, 1, wfo);
    repack_mfma<<<dim3(144), 256, 0, stream>>>(w1, w1, 64, 64, 64, 2, wf1);
    repack_mfma<<<dim3(144), 256, 0, stream>>>(w2, w2, 64, 64, 64, 2, wf2);
    repack_mfma<<<dim3(144), 256, 0, stream>>>(w_last, w_last, 64, 64, 64, 2, wfl);
    bias_concat_kernel<<<dim3(1), 64, 0, stream>>>(b_off1, b_off2, bias54);

    to_nhwc<<<dim3(512), 256, 0, stream>>>(input, offset, xn, offn);

    // offset conv (54 oc) from NHWC offset -> om (NCHW fp32)
    conv_direct<32, 54><<<dim3(1024), 256, 0, stream>>>(offn, wfo, bias54, om);
    // DCN 1: sample xn, leaky -> x1n (NHWC bf16)
    dcn_direct<0><<<dim3(1024), 256, 0, stream>>>(xn, om, 0, wf1, b1, nullptr, x1n);
    // DCN 2: sample x1n, + input residual -> x2n (NHWC bf16)
    dcn_direct<1><<<dim3(1024), 256, 0, stream>>>(x1n, om, 27, wf2, b2, input, x2n);
    // final conv from x2n -> out (NCHW fp32)
    conv_direct<64, 64><<<dim3(1024), 256, 0, stream>>>(x2n, wfl, b_last, out);
}

// Round 5
// 144.080 us; speedup vs baseline: 4.4706x; 1.0631x over previous
//
#include <hip/hip_runtime.h>
#include <cmath>

#define HW   16384
#define Wd   128
#define Hd   128
#define NB   4

typedef __attribute__((ext_vector_type(8))) short bf16x8;
typedef __attribute__((ext_vector_type(4))) float f32x4;
typedef __attribute__((ext_vector_type(4))) unsigned int u32x4;

__device__ inline unsigned short f2bf(float f) {
    unsigned u = __builtin_bit_cast(unsigned, f);
    unsigned r = (u + 0x7FFFu + ((u >> 16) & 1u)) >> 16;
    return (unsigned short)r;
}
__device__ inline float bflo(unsigned w) { return __builtin_bit_cast(float, w << 16); }
__device__ inline float bfhi(unsigned w) { return __builtin_bit_cast(float, w & 0xFFFF0000u); }

// ---------- weight repack into MFMA A-fragment-linear bf16 ----------
// dst: [9][4 m][KS][64 lane][8 e]; (k,m,ks,lane,e) <- w[oc][c][k], oc=m*16+(lane&15),
// c=ks*32+(lane>>4)*8+e; src1 for oc<Osplit else src2; zero-pad OOB.
__global__ void repack_mfma(const float* __restrict__ src1, const float* __restrict__ src2,
                            int Osplit, int O, int CIN, int KS, unsigned short* __restrict__ dst) {
    int idx = blockIdx.x * 256 + threadIdx.x;
    int total = 9 * 4 * KS * 64 * 8;
    if (idx >= total) return;
    int e    = idx & 7;
    int lane = (idx >> 3) & 63;
    int ks   = (idx >> 9) % KS;
    int m    = (idx / (512 * KS)) & 3;
    int k    = idx / (2048 * KS);
    int oc = m * 16 + (lane & 15);
    int c  = ks * 32 + (lane >> 4) * 8 + e;
    float v = 0.f;
    if (oc < O && c < CIN) {
        const float* s = (oc < Osplit) ? src1 + ((size_t)oc * CIN + c) * 9 + k
                                       : src2 + ((size_t)(oc - Osplit) * CIN + c) * 9 + k;
        v = *s;
    }
    dst[idx] = f2bf(v);
}

__global__ void bias_concat_kernel(const float* __restrict__ b1, const float* __restrict__ b2,
                                   float* __restrict__ dst) {
    int t = threadIdx.x;
    if (t < 27) dst[t] = b1[t];
    else if (t < 54) dst[t] = b2[t - 27];
}

// ---------- NCHW fp32 -> NHWC bf16, 16B-vectorized stores ----------
__global__ __launch_bounds__(256) void to_nhwc(const float* __restrict__ xin,
                                               const float* __restrict__ off,
                                               unsigned short* __restrict__ xn,
                                               unsigned short* __restrict__ offn) {
    int t = blockIdx.x * 256 + threadIdx.x;
    if (t < 65536) {
        int b = t >> 14, p = t & 16383;
        const float* s = xin + ((size_t)b * 64) * HW + p;
        unsigned short* d = xn + (size_t)t * 64;
#pragma unroll
        for (int g = 0; g < 8; g++) {
            unsigned short pk[8];
#pragma unroll
            for (int e = 0; e < 8; e++) pk[e] = f2bf(s[(size_t)(g * 8 + e) * HW]);
            *(bf16x8*)(d + g * 8) = *(bf16x8*)pk;
        }
    } else {
        int u = t - 65536;
        int b = u >> 14, p = u & 16383;
        const float* s = off + ((size_t)b * 32) * HW + p;
        unsigned short* d = offn + (size_t)u * 32;
#pragma unroll
        for (int g = 0; g < 4; g++) {
            unsigned short pk[8];
#pragma unroll
            for (int e = 0; e < 8; e++) pk[e] = f2bf(s[(size_t)(g * 8 + e) * HW]);
            *(bf16x8*)(d + g * 8) = *(bf16x8*)pk;
        }
    }
}

// ---------- LDS-free direct conv3x3, 1-tap lookahead on B ----------
template<int CIN, int OCT>
__global__ __launch_bounds__(256, 4) void conv_direct(
    const unsigned short* __restrict__ xn, const unsigned short* __restrict__ wf,
    const float* __restrict__ bias, float* __restrict__ out)
{
    constexpr int KS = CIN / 32;
    int lb = ((blockIdx.x & 7) << 7) | (blockIdx.x >> 3);   // XCD-chunked swizzle
    int t = threadIdx.x;
    int lane = t & 63, wv = t >> 6;
    int px = lb * 64 + wv * 16 + (lane & 15);
    int b = px >> 14, p = px & 16383;
    int row = p >> 7, col = p & 127;
    int cg = lane >> 4;

    const bf16x8* wfv = (const bf16x8*)wf;
    f32x4 acc[4];
#pragma unroll
    for (int m = 0; m < 4; m++) acc[m] = (f32x4){0.f, 0.f, 0.f, 0.f};

    auto loadB = [&](int k, bf16x8* bq) {
        int hh = row + k / 3 - 1, ww = col + k % 3 - 1;
        bool ok = (hh >= 0) & (hh < Hd) & (ww >= 0) & (ww < Wd);
        size_t base = ((size_t)(b << 14) + hh * Wd + ww) * CIN;
#pragma unroll
        for (int ks = 0; ks < KS; ks++) {
            bf16x8 v = (bf16x8){0, 0, 0, 0, 0, 0, 0, 0};
            if (ok) v = *(const bf16x8*)(xn + base + ks * 32 + cg * 8);
            bq[ks] = v;
        }
    };

    bf16x8 bq[KS];
    loadB(0, bq);

#pragma unroll
    for (int k = 0; k < 9; k++) {
        bf16x8 aF[4 * KS];
#pragma unroll
        for (int m = 0; m < 4; m++)
#pragma unroll
            for (int ks = 0; ks < KS; ks++)
                aF[m * KS + ks] = wfv[((k * 4 + m) * KS + ks) * 64 + lane];

        bf16x8 bn[KS];
        if (k < 8) loadB(k + 1, bn);

#pragma unroll
        for (int ks = 0; ks < KS; ks++)
#pragma unroll
            for (int m = 0; m < 4; m++)
                acc[m] = __builtin_amdgcn_mfma_f32_16x16x32_bf16(aF[m * KS + ks], bq[ks], acc[m], 0, 0, 0);

        if (k < 8) {
#pragma unroll
            for (int ks = 0; ks < KS; ks++) bq[ks] = bn[ks];
        }
    }

#pragma unroll
    for (int m = 0; m < 4; m++) {
        int ocb = m * 16 + cg * 4;
#pragma unroll
        for (int r = 0; r < 4; r++) {
            int oc = ocb + r;
            if (OCT == 64 || oc < OCT)
                out[((size_t)b * OCT + oc) * HW + p] = acc[m][r] + bias[oc];
        }
    }
}

// ---------- DCNv2 direct, 1-tap lookahead software pipeline ----------
struct Tap { float w00, w01, w10, w11; int o00, o01, o10, o11; };

__device__ inline Tap mkparams(float oy, float ox, float mv, int row, int col, int k) {
    Tap P;
    float mk = 1.f / (1.f + __expf(-mv));
    float ys = (float)(row + k / 3 - 1) + oy;
    float xs = (float)(col + k % 3 - 1) + ox;
    float y0f = floorf(ys), x0f = floorf(xs);
    float fy = ys - y0f, fx = xs - x0f;
    int y0 = (int)y0f, x0 = (int)x0f;
    int y1 = y0 + 1, x1 = x0 + 1;
    bool vy0 = (y0 >= 0) & (y0 < Hd);
    bool vy1 = (y1 >= 0) & (y1 < Hd);
    bool vx0 = (x0 >= 0) & (x0 < Wd);
    bool vx1 = (x1 >= 0) & (x1 < Wd);
    P.w00 = (vy0 && vx0) ? (1.f - fy) * (1.f - fx) * mk : 0.f;
    P.w01 = (vy0 && vx1) ? (1.f - fy) * fx * mk : 0.f;
    P.w10 = (vy1 && vx0) ? fy * (1.f - fx) * mk : 0.f;
    P.w11 = (vy1 && vx1) ? fy * fx * mk : 0.f;
    int iy0 = min(max(y0, 0), Hd - 1) * Wd;
    int iy1 = min(max(y1, 0), Hd - 1) * Wd;
    int ix0 = min(max(x0, 0), Wd - 1);
    int ix1 = min(max(x1, 0), Wd - 1);
    P.o00 = iy0 + ix0; P.o01 = iy0 + ix1; P.o10 = iy1 + ix0; P.o11 = iy1 + ix1;
    return P;
}

struct G4 { u32x4 a, b, c, d; };
__device__ inline G4 gather4(const unsigned short* __restrict__ xb, const Tap& P, int c0) {
    G4 g;
    g.a = *(const u32x4*)(xb + (size_t)P.o00 * 64 + c0);
    g.b = *(const u32x4*)(xb + (size_t)P.o01 * 64 + c0);
    g.c = *(const u32x4*)(xb + (size_t)P.o10 * 64 + c0);
    g.d = *(const u32x4*)(xb + (size_t)P.o11 * 64 + c0);
    return g;
}

__device__ inline bf16x8 combine4(const G4& g, const Tap& P) {
    unsigned ow[4];
#pragma unroll
    for (int wd = 0; wd < 4; wd++) {
        float slo = P.w00 * bflo(g.a[wd]);
        slo = fmaf(P.w01, bflo(g.b[wd]), slo);
        slo = fmaf(P.w10, bflo(g.c[wd]), slo);
        slo = fmaf(P.w11, bflo(g.d[wd]), slo);
        float shi = P.w00 * bfhi(g.a[wd]);
        shi = fmaf(P.w01, bfhi(g.b[wd]), shi);
        shi = fmaf(P.w10, bfhi(g.c[wd]), shi);
        shi = fmaf(P.w11, bfhi(g.d[wd]), shi);
        ow[wd] = (unsigned)f2bf(slo) | ((unsigned)f2bf(shi) << 16);
    }
    u32x4 r = {ow[0], ow[1], ow[2], ow[3]};
    return __builtin_bit_cast(bf16x8, r);
}

// EPI 0: leaky -> outn (NHWC bf16). EPI 1: +resid(NCHW fp32) -> outn (NHWC bf16).
template<int EPI>
__global__ __launch_bounds__(256, 4) void dcn_direct(
    const unsigned short* __restrict__ xn, const float* __restrict__ om, int omOff,
    const unsigned short* __restrict__ wf, const float* __restrict__ bias,
    const float* __restrict__ resid, unsigned short* __restrict__ outn)
{
    int lb = ((blockIdx.x & 7) << 7) | (blockIdx.x >> 3);
    int t = threadIdx.x;
    int lane = t & 63, wv = t >> 6;
    int px = lb * 64 + wv * 16 + (lane & 15);
    int b = px >> 14, p = px & 16383;
    int row = p >> 7, col = p & 127;
    int cg = lane >> 4;
    int c0a = cg * 8;
    int c0b = 32 + cg * 8;

    const float* omb = om + ((size_t)b * 54 + omOff) * HW + p;
    const unsigned short* xb = xn + ((size_t)(b << 14)) * 64;
    const bf16x8* wfv = (const bf16x8*)wf;

    f32x4 acc[4];
#pragma unroll
    for (int m = 0; m < 4; m++) acc[m] = (f32x4){0.f, 0.f, 0.f, 0.f};

    // prologue: tap 0 params + gathers
    float o0y = omb[0], o0x = omb[(size_t)1 * HW], m0 = omb[(size_t)18 * HW];
    Tap P0 = mkparams(o0y, o0x, m0, row, col, 0);
    G4 GA = gather4(xb, P0, c0a);
    G4 GB = gather4(xb, P0, c0b);

#pragma unroll
    for (int k = 0; k < 9; k++) {
        // issue next tap's om loads first (latency hidden under this tap's work)
        float n_oy = 0.f, n_ox = 0.f, n_mv = 0.f;
        if (k < 8) {
            n_oy = omb[(size_t)(2 * k + 2) * HW];
            n_ox = omb[(size_t)(2 * k + 3) * HW];
            n_mv = omb[(size_t)(19 + k) * HW];
        }
        // this tap's weight fragments
        bf16x8 aF[8];
#pragma unroll
        for (int m = 0; m < 4; m++)
#pragma unroll
            for (int ks = 0; ks < 2; ks++)
                aF[m * 2 + ks] = wfv[((k * 4 + m) * 2 + ks) * 64 + lane];

        // ks=0: combine + MFMA
        bf16x8 bF0 = combine4(GA, P0);
#pragma unroll
        for (int m = 0; m < 4; m++)
            acc[m] = __builtin_amdgcn_mfma_f32_16x16x32_bf16(aF[m * 2 + 0], bF0, acc[m], 0, 0, 0);

        Tap P1;
        if (k < 8) {
            P1 = mkparams(n_oy, n_ox, n_mv, row, col, k + 1);
            GA = gather4(xb, P1, c0a);      // next tap ks=0 in flight
        }

        // ks=1: combine + MFMA
        bf16x8 bF1 = combine4(GB, P0);
#pragma unroll
        for (int m = 0; m < 4; m++)
            acc[m] = __builtin_amdgcn_mfma_f32_16x16x32_bf16(aF[m * 2 + 1], bF1, acc[m], 0, 0, 0);

        if (k < 8) {
            GB = gather4(xb, P1, c0b);      // next tap ks=1 in flight
            P0 = P1;
        }
    }

    // epilogue: NHWC bf16 out
    unsigned short* drow = outn + (size_t)px * 64;
#pragma unroll
    for (int m = 0; m < 4; m++) {
        int ocb = m * 16 + cg * 4;
        unsigned short pk[4];
#pragma unroll
        for (int r = 0; r < 4; r++) {
            int oc = ocb + r;
            float v = acc[m][r] + bias[oc];
            if (EPI == 0) v = (v >= 0.f) ? v : 0.01f * v;
            if (EPI == 1) v += resid[((size_t)b * 64 + oc) * HW + p];
            pk[r] = f2bf(v);
        }
        *(ushort4*)(drow + ocb) = *(ushort4*)pk;
    }
}

extern "C" void kernel_launch(void* const* d_in, const int* in_sizes, int n_in,
                              void* d_out, int out_size, void* d_ws, size_t ws_size,
                              hipStream_t stream)
{
    const float* input  = (const float*)d_in[0];
    const float* offset = (const float*)d_in[1];
    const float* w_off1 = (const float*)d_in[2];
    const float* b_off1 = (const float*)d_in[3];
    const float* w1     = (const float*)d_in[4];
    const float* b1     = (const float*)d_in[5];
    const float* w_off2 = (const float*)d_in[6];
    const float* b_off2 = (const float*)d_in[7];
    const float* w2     = (const float*)d_in[8];
    const float* b2     = (const float*)d_in[9];
    const float* w_last = (const float*)d_in[10];
    const float* b_last = (const float*)d_in[11];
    float* out = (float*)d_out;

    float* ws = (float*)d_ws;
    float* om = ws;                                        // 3,538,944 f
    unsigned short* xn   = (unsigned short*)(om + 3538944);   // 4,194,304 ush
    unsigned short* offn = xn + 4194304;                   // 2,097,152 ush
    unsigned short* x1n  = offn + 2097152;                 // 4,194,304 ush
    unsigned short* x2n  = x1n + 4194304;                  // 4,194,304 ush
    unsigned short* wfo  = x2n + 4194304;                  // 18,432 ush
    unsigned short* wf1  = wfo + 18432;                    // 36,864 ush
    unsigned short* wf2  = wf1 + 36864;                    // 36,864 ush
    unsigned short* wfl  = wf2 + 36864;                    // 36,864 ush
    float* bias54 = (float*)(wfl + 36864);                 // 64 f

    repack_mfma<<<dim3(72),  256, 0, stream>>>(w_off1, w_off2, 27, 54, 32, 1, wfo);
    repack_mfma<<<dim3(144), 256, 0, stream>>>(w1, w1, 64, 64, 64, 2, wf1);
    repack_mfma<<<dim3(144), 256, 0, stream>>>(w2, w2, 64, 64, 64, 2, wf2);
    repack_mfma<<<dim3(144), 256, 0, stream>>>(w_last, w_last, 64, 64, 64, 2, wfl);
    bias_concat_kernel<<<dim3(1), 64, 0, stream>>>(b_off1, b_off2, bias54);

    // 131072 threads = 512 blocks (input 65536 px + offset 65536 px) — R4's 384 was the bug
    to_nhwc<<<dim3(512), 256, 0, stream>>>(input, offset, xn, offn);

    // offset conv (54 oc) from NHWC offset -> om (NCHW fp32)
    conv_direct<32, 54><<<dim3(1024), 256, 0, stream>>>(offn, wfo, bias54, om);
    // DCN 1: sample xn, leaky -> x1n (NHWC bf16)
    dcn_direct<0><<<dim3(1024), 256, 0, stream>>>(xn, om, 0, wf1, b1, nullptr, x1n);
    // DCN 2: sample x1n, + input residual -> x2n (NHWC bf16)
    dcn_direct<1><<<dim3(1024), 256, 0, stream>>>(x1n, om, 27, wf2, b2, input, x2n);
    // final conv from x2n -> out (NCHW fp32)
    conv_direct<64, 64><<<dim3(1024), 256, 0, stream>>>(x2n, wfl, b_last, out);
}